// Round 7
// baseline (1277.337 us; speedup 1.0000x reference)
//
#include <hip/hip_runtime.h>
#include <hip/hip_bf16.h>
#include <math.h>

#define BATCH   1024
#define SEQ     80
#define EMB     512
#define UNITS   512
#define NBG     16           // batch groups of 64 rows
#define NJ      8            // col groups of 64 cols
#define THREADS 512          // 8 waves; wave w: row-grp w>>1, col-pair w&1

#define H0_OFF (2u * 1024 * 1024)
#define H1_OFF (4u * 1024 * 1024)
#define FL_OFF (6u * 1024 * 1024)

typedef __attribute__((ext_vector_type(8))) short              bf16x8;
typedef __attribute__((ext_vector_type(8))) unsigned short     u16x8;
typedef __attribute__((ext_vector_type(4))) float              f32x4;
typedef __attribute__((ext_vector_type(2))) unsigned long long u64x2;

__device__ inline unsigned short f2bf(float f) {
    __hip_bfloat16 h = __float2bfloat16(f);
    return *reinterpret_cast<unsigned short*>(&h);
}
__device__ inline float bf2f(unsigned short u) {
    unsigned int x = ((unsigned int)u) << 16;
    return __uint_as_float(x);
}
__device__ inline float tanh_fast(float x) {
    float e = __expf(2.f * x);
    return 1.f - 2.f / (e + 1.f);
}
__device__ inline u16x8 pack8(float4 p0, float4 p1) {
    u16x8 v;
    v[0]=f2bf(p0.x); v[1]=f2bf(p0.y); v[2]=f2bf(p0.z); v[3]=f2bf(p0.w);
    v[4]=f2bf(p1.x); v[5]=f2bf(p1.y); v[6]=f2bf(p1.z); v[7]=f2bf(p1.w);
    return v;
}
__device__ inline void st_u16(unsigned short* p, unsigned short v) {
    __hip_atomic_store(p, v, __ATOMIC_RELAXED, __HIP_MEMORY_SCOPE_AGENT);
}
__device__ inline unsigned long long ld_u64(const unsigned long long* p) {
    return __hip_atomic_load(p, __ATOMIC_RELAXED, __HIP_MEMORY_SCOPE_AGENT);
}
__device__ inline int ld_flag(const int* p) {
    return __hip_atomic_load(p, __ATOMIC_RELAXED, __HIP_MEMORY_SCOPE_AGENT);
}

// ---------------------------------------------------------------------------
// Pack weights, frag-order, per (type, j) 128KB block image:
// g = ((type*8 + j)*2 + mat)*64 + kk*4 + nt  (g = 0..2047, slab = 1KB)
// type0: mat0=W0x mat1=W0h ; type1: mat0=W1x mat1=W1h
// elem(lane,jj) = M[kk*32 + (lane>>4)*8 + jj][j*64 + nt*16 + (lane&15)]
// ---------------------------------------------------------------------------
__global__ __launch_bounds__(256) void pack_weights(
    const float* __restrict__ W0x, const float* __restrict__ W0h,
    const float* __restrict__ W1x, const float* __restrict__ W1h,
    unsigned short* __restrict__ wpack)
{
    int g    = blockIdx.x * 4 + (threadIdx.x >> 6);   // 0..2047
    int lane = threadIdx.x & 63;
    int type = g >> 10;
    int j    = (g >> 7) & 7;
    int mat  = (g >> 6) & 1;
    int kk   = (g >> 2) & 15;
    int nt   = g & 3;
    const float* M = type ? (mat ? W1h : W1x) : (mat ? W0h : W0x);
    int col  = j * 64 + nt * 16 + (lane & 15);
    int rowb = kk * 32 + (lane >> 4) * 8;

    u16x8 v;
#pragma unroll
    for (int jj = 0; jj < 8; ++jj)
        v[jj] = f2bf(M[(size_t)(rowb + jj) * UNITS + col]);
    *(u16x8*)(wpack + (size_t)g * 512 + lane * 8) = v;
}

// LDS layouts (ushort offsets)
#define WLD(mat, kk, nt)            ((((mat)*16 + (kk))*4 + (nt)) * 512)
#define RNG(slot, kkl, row, quad)   (((((slot)*2 + (kkl))*64 + (row))*4 + (quad)) * 8)

// gather h-tile [64r x 512] from HB (parity PAR) through the 2-slot ring,
// rolling 3-slice prefetch; accumulate A0/A1 += h @ Wmat (LDS-resident B).
#define GATHER_GEMM(HB, PAR, MAT, A0, A1)                                      \
    do {                                                                       \
        const unsigned long long* hs_ = (const unsigned long long*)            \
            ((HB) + ((size_t)(PAR) * BATCH + rbase) * UNITS);                  \
        const int go_ = grow * 128 + gk8 * 2;                                  \
        u64x2 ld_[8];                                                          \
        _Pragma("unroll")                                                      \
        for (int s_ = 0; s_ < 3; ++s_) {                                       \
            ld_[s_][0] = ld_u64(hs_ + go_ + s_ * 16);                          \
            ld_[s_][1] = ld_u64(hs_ + go_ + s_ * 16 + 1);                      \
        }                                                                      \
        _Pragma("unroll")                                                      \
        for (int s_ = 0; s_ < 8; ++s_) {                                       \
            *(u64x2*)(ring + RNG(s_ & 1, gk8 >> 2, grow, gk8 & 3)) = ld_[s_];  \
            __syncthreads();                                                   \
            if (s_ + 3 < 8) {                                                  \
                ld_[s_+3][0] = ld_u64(hs_ + go_ + (s_+3) * 16);                \
                ld_[s_+3][1] = ld_u64(hs_ + go_ + (s_+3) * 16 + 1);            \
            }                                                                  \
            _Pragma("unroll")                                                  \
            for (int kl_ = 0; kl_ < 2; ++kl_) {                                \
                bf16x8 a_ = *(const bf16x8*)(ring + RNG(s_ & 1, kl_, arow, quad)); \
                int kg_ = s_ * 2 + kl_;                                        \
                A0 = __builtin_amdgcn_mfma_f32_16x16x32_bf16(a_,               \
                    *(const bf16x8*)(wlds + WLD(MAT, kg_, nt0) + lane*8), A0, 0,0,0); \
                A1 = __builtin_amdgcn_mfma_f32_16x16x32_bf16(a_,               \
                    *(const bf16x8*)(wlds + WLD(MAT, kg_, nt1) + lane*8), A1, 0,0,0); \
            }                                                                  \
        }                                                                      \
    } while (0)

// stage x(TT) [64r x 512] from emb through the ring; A0/A1 += x @ W0x (mat 0)
#define XSTAGE_GEMM(TT, A0, A1)                                                \
    do {                                                                       \
        int t_   = (TT) < SEQ ? (TT) : SEQ - 1;                                \
        int idx_ = inputs[(rbase + grow) * SEQ + t_];                          \
        const float4* ep_ = (const float4*)(emb + (size_t)idx_ * EMB) + gk8*2; \
        float4 pa_[8], pb_[8];                                                 \
        _Pragma("unroll")                                                      \
        for (int s_ = 0; s_ < 3; ++s_) { pa_[s_] = ep_[s_*16]; pb_[s_] = ep_[s_*16+1]; } \
        _Pragma("unroll")                                                      \
        for (int s_ = 0; s_ < 8; ++s_) {                                       \
            *(u16x8*)(ring + RNG(s_ & 1, gk8 >> 2, grow, gk8 & 3)) =           \
                pack8(pa_[s_], pb_[s_]);                                       \
            __syncthreads();                                                   \
            if (s_ + 3 < 8) { pa_[s_+3] = ep_[(s_+3)*16]; pb_[s_+3] = ep_[(s_+3)*16+1]; } \
            _Pragma("unroll")                                                  \
            for (int kl_ = 0; kl_ < 2; ++kl_) {                                \
                bf16x8 a_ = *(const bf16x8*)(ring + RNG(s_ & 1, kl_, arow, quad)); \
                int kg_ = s_ * 2 + kl_;                                        \
                A0 = __builtin_amdgcn_mfma_f32_16x16x32_bf16(a_,               \
                    *(const bf16x8*)(wlds + WLD(0, kg_, nt0) + lane*8), A0, 0,0,0); \
                A1 = __builtin_amdgcn_mfma_f32_16x16x32_bf16(a_,               \
                    *(const bf16x8*)(wlds + WLD(0, kg_, nt1) + lane*8), A1, 0,0,0); \
            }                                                                  \
        }                                                                      \
    } while (0)

#define PUBLISH(HB, PAR, A0, A1)                                               \
    do {                                                                       \
        unsigned short* d_ = (HB) +                                            \
            ((size_t)(PAR) * BATCH + rbase + rg * 16 + quad * 4) * UNITS       \
            + c0 + l15;                                                        \
        _Pragma("unroll")                                                      \
        for (int i_ = 0; i_ < 4; ++i_) {                                       \
            st_u16(d_ + (size_t)i_ * UNITS + nt0 * 16, f2bf(tanh_fast(A0[i_]))); \
            st_u16(d_ + (size_t)i_ * UNITS + nt1 * 16, f2bf(tanh_fast(A1[i_]))); \
        }                                                                      \
    } while (0)

// ---------------------------------------------------------------------------
// 256 blocks = 2 types x 16 bg x 8 j, co-resident 1/CU (144KB LDS).
// L0 (type 0): h0(r) = tanh(b0 + x_r@W0x + h0(r-1)@W0h); W0x,W0h in LDS.
//   x@W0x computed in the post-flag shadow of the previous round.
// L1 (type 1): h1(s) = tanh(b1 + h0(s)@W1x + h1(s-1)@W1h); W1x,W1h in LDS.
// Spins: L0 r: F0>=r, F1>=r-1.  L1 s: F0>=s+1, F1>=s.  (throttles subsumed)
// Publish/spin/fence/barrier protocol identical to the validated baseline.
// ---------------------------------------------------------------------------
__global__ __launch_bounds__(THREADS, 1) void rnn_ls(
    const int*   __restrict__ inputs,
    const float* __restrict__ emb,
    const float* __restrict__ b0,
    const float* __restrict__ b1,
    const unsigned short* __restrict__ wpack,
    unsigned short* __restrict__ h0buf,   // [2][1024][512] bf16 (par1 zeroed)
    unsigned short* __restrict__ h1buf,   // [2][1024][512] bf16 (par1 zeroed)
    int* __restrict__ flag0,              // [16][8]
    int* __restrict__ flag1,              // [16][8]
    const float* __restrict__ Wout,
    const float* __restrict__ bout,
    float*       __restrict__ out)
{
    __shared__ __align__(16) unsigned short wlds[2 * 16 * 4 * 512];  // 128KB
    __shared__ __align__(16) unsigned short ring[2 * 2 * 64 * 4 * 8]; // 16KB

    const int tid   = threadIdx.x;
    const int w     = tid >> 6;
    const int lane  = tid & 63;
    const int quad  = lane >> 4;
    const int l15   = lane & 15;
    const int type  = blockIdx.x >> 7;    // 0 = L0, 1 = L1
    const int bidx  = blockIdx.x & 127;
    const int bg    = bidx >> 3;          // 0..15
    const int j     = bidx & 7;           // 0..7
    const int rbase = bg * 64;
    const int c0    = j * 64;

    const int rg   = w >> 1;              // row-group 0..3 (16 rows each)
    const int ntp  = w & 1;
    const int nt0  = 2 * ntp, nt1 = nt0 + 1;
    const int arow = rg * 16 + l15;       // A-frag row
    const int grow = tid >> 3;            // staging row 0..63
    const int gk8  = tid & 7;             // staging k-part

    // ---- stage this block's 128KB weight image into LDS ----
    {
        const unsigned short* wsrc = wpack + (size_t)(type * 8 + j) * 128 * 512;
#pragma unroll
        for (int i = 0; i < 16; ++i)
            *(u16x8*)(wlds + (size_t)(i * 512 + tid) * 8) =
                *(const u16x8*)(wsrc + (size_t)(i * 512 + tid) * 8);
    }
    __syncthreads();

    const float* bp   = type ? b1 : b0;
    const float  bia0 = bp[c0 + nt0 * 16 + l15];
    const float  bia1 = bp[c0 + nt1 * 16 + l15];

    if (type == 0) {
        // =================== L0: h0 recurrence ===================
        f32x4 aX0 = {bia0, bia0, bia0, bia0};
        f32x4 aX1 = {bia1, bia1, bia1, bia1};
        XSTAGE_GEMM(0, aX0, aX1);                     // preX(0)

        for (int r = 0; r < SEQ; ++r) {
            const int par = r & 1;
            if (tid < 8)
                while (ld_flag(flag0 + bg * 8 + tid) < r)
                    __builtin_amdgcn_s_sleep(1);
            else if (tid < 16)
                while (ld_flag(flag1 + bg * 8 + (tid - 8)) < r - 1)
                    __builtin_amdgcn_s_sleep(1);
            __asm__ volatile("" ::: "memory");
            __syncthreads();

            f32x4 a0 = aX0, a1 = aX1;
            GATHER_GEMM(h0buf, par ^ 1, 1, a0, a1);   // + h0(r-1) @ W0h
            PUBLISH(h0buf, par, a0, a1);              // h0(r)
            __syncthreads();                          // drain publishes
            if (tid == 0)
                __hip_atomic_store(flag0 + bg * 8 + j, r + 1,
                                   __ATOMIC_RELEASE, __HIP_MEMORY_SCOPE_AGENT);

            // shadow: preX(r+1) = b0 + x(r+1) @ W0x
            aX0 = (f32x4){bia0, bia0, bia0, bia0};
            aX1 = (f32x4){bia1, bia1, bia1, bia1};
            XSTAGE_GEMM(r + 1, aX0, aX1);
        }
    } else {
        // =================== L1: h1 recurrence + epilogue ===================
        for (int s = 0; s < SEQ; ++s) {
            const int par = s & 1;
            if (tid < 8)
                while (ld_flag(flag0 + bg * 8 + tid) < s + 1)
                    __builtin_amdgcn_s_sleep(1);
            else if (tid < 16)
                while (ld_flag(flag1 + bg * 8 + (tid - 8)) < s)
                    __builtin_amdgcn_s_sleep(1);
            __asm__ volatile("" ::: "memory");
            __syncthreads();

            f32x4 a0 = {bia0, bia0, bia0, bia0};
            f32x4 a1 = {bia1, bia1, bia1, bia1};
            GATHER_GEMM(h0buf, par,     0, a0, a1);   // + h0(s)   @ W1x
            GATHER_GEMM(h1buf, par ^ 1, 1, a0, a1);   // + h1(s-1) @ W1h
            PUBLISH(h1buf, par, a0, a1);              // h1(s)
            __syncthreads();                          // drain publishes
            if (tid == 0)
                __hip_atomic_store(flag1 + bg * 8 + j, s + 1,
                                   __ATOMIC_RELEASE, __HIP_MEMORY_SCOPE_AGENT);
        }

        // epilogue: j==0 blocks reduce h1(79) (parity 1) -> out
        if (j == 0) {
            if (tid < 8)
                while (ld_flag(flag1 + bg * 8 + tid) < SEQ)
                    __builtin_amdgcn_s_sleep(1);
            __asm__ volatile("" ::: "memory");
            __syncthreads();
            const unsigned long long* hs = (const unsigned long long*)
                (h1buf + ((size_t)((SEQ - 1) & 1) * BATCH + rbase) * UNITS);
#pragma unroll
            for (int i = 0; i < 8; ++i) {
                int row = w * 8 + i;
                unsigned long long q0 = ld_u64(hs + row * 128 + lane * 2);
                unsigned long long q1 = ld_u64(hs + row * 128 + lane * 2 + 1);
                u64x2 qq; qq[0] = q0; qq[1] = q1;
                u16x8 hv = *(u16x8*)&qq;
                float sacc = 0.f;
#pragma unroll
                for (int k = 0; k < 8; ++k)
                    sacc += bf2f(hv[k]) * Wout[lane * 8 + k];
#pragma unroll
                for (int off = 32; off > 0; off >>= 1)
                    sacc += __shfl_down(sacc, off);
                if (lane == 0) {
                    float z = sacc + bout[0];
                    out[rbase + row] = 1.f / (1.f + __expf(-z));
                }
            }
        }
    }
}

extern "C" void kernel_launch(void* const* d_in, const int* in_sizes, int n_in,
                              void* d_out, int out_size, void* d_ws, size_t ws_size,
                              hipStream_t stream) {
    const int*   inputs = (const int*)d_in[0];
    const float* emb    = (const float*)d_in[1];
    const float* W0x    = (const float*)d_in[2];
    const float* W0h    = (const float*)d_in[3];
    const float* b0     = (const float*)d_in[4];
    const float* W1x    = (const float*)d_in[5];
    const float* W1h    = (const float*)d_in[6];
    const float* b1     = (const float*)d_in[7];
    const float* Wout   = (const float*)d_in[8];
    const float* bout   = (const float*)d_in[9];
    float*       out    = (float*)d_out;

    unsigned short* wpack = (unsigned short*)d_ws;                      // 2 MB
    unsigned short* h0buf = (unsigned short*)((char*)d_ws + H0_OFF);    // 2 MB
    unsigned short* h1buf = (unsigned short*)((char*)d_ws + H1_OFF);    // 2 MB
    int* flag0 = (int*)((char*)d_ws + FL_OFF);                          // 512 B
    int* flag1 = flag0 + 128;                                           // 512 B

    hipMemsetAsync((char*)d_ws + FL_OFF, 0, 1024, stream);
    // zero parity-1 halves: h0(-1) = h1(-1) = 0
    hipMemsetAsync((char*)h0buf + (size_t)BATCH * UNITS * 2, 0,
                   (size_t)BATCH * UNITS * 2, stream);
    hipMemsetAsync((char*)h1buf + (size_t)BATCH * UNITS * 2, 0,
                   (size_t)BATCH * UNITS * 2, stream);
    pack_weights<<<512, 256, 0, stream>>>(W0x, W0h, W1x, W1h, wpack);
    rnn_ls<<<256, THREADS, 0, stream>>>(
        inputs, emb, b0, b1, wpack, h0buf, h1buf, flag0, flag1,
        Wout, bout, out);
}